// Round 2
// baseline (463.746 us; speedup 1.0000x reference)
//
#include <hip/hip_runtime.h>
#include <hip/hip_bf16.h>

// Problem constants (fixed by reference)
static constexpr int Nn  = 8192;     // nodes
static constexpr int Hh  = 4;        // heads
static constexpr int Ee  = 131072;   // edges
static constexpr int DK  = 16;       // per-head feature dim
static constexpr int TBL = 1 << 20;  // hash table slots (load factor ~0.25)
static constexpr int TBLMASK = TBL - 1;
static constexpr int XLEN = Hh * Nn * DK;  // 524288 floats, same flat layout as h / out

// ---------------------------------------------------------------------------
// Kernel 1: initialize hash table, rowsums, per-row counters, global count
__global__ void init_kernel(int* __restrict__ tbl_key, int* __restrict__ tbl_val,
                            float* __restrict__ rowsum, int* __restrict__ row_cnt,
                            int* __restrict__ row_fill, int* __restrict__ count) {
    int i = blockIdx.x * blockDim.x + threadIdx.x;
    if (i < TBL) { tbl_key[i] = -1; tbl_val[i] = -1; }
    if (i < Hh * Nn) rowsum[i] = 0.0f;
    if (i < Nn) { row_cnt[i] = 0; row_fill[i] = 0; }
    if (i == 0) *count = 0;
}

// ---------------------------------------------------------------------------
// Kernel 2: insert all 2E directed entries; winner per (u,v) = max combined t.
// t < E  : (u,v) = (src[t], dst[t])        (first scatter)
// t >= E : (u,v) = (dst[t-E], src[t-E])    (second scatter, outranks first)
// This reproduces numpy sequential last-write-wins scatter semantics exactly.
__global__ void insert_kernel(const int* __restrict__ src, const int* __restrict__ dst,
                              int* __restrict__ tbl_key, int* __restrict__ tbl_val) {
    int t = blockIdx.x * blockDim.x + threadIdx.x;
    if (t >= 2 * Ee) return;
    int u, v;
    if (t < Ee) { u = src[t]; v = dst[t]; }
    else        { u = dst[t - Ee]; v = src[t - Ee]; }
    unsigned key = ((unsigned)u << 13) | (unsigned)v;   // N = 2^13
    unsigned idx = ((key * 2654435761u) >> 6) & TBLMASK;
    while (true) {
        int existing = atomicCAS(&tbl_key[idx], -1, (int)key);
        if (existing == -1 || existing == (int)key) {
            atomicMax(&tbl_val[idx], t);
            break;
        }
        idx = (idx + 1) & TBLMASK;
    }
}

// ---------------------------------------------------------------------------
// Kernel 3: compact winners, accumulate per-head row sums + per-row counts
__global__ void compact_kernel(const int* __restrict__ tbl_key, const int* __restrict__ tbl_val,
                               const float* __restrict__ e,
                               int* __restrict__ rows, int* __restrict__ cols,
                               int* __restrict__ eidx, float* __restrict__ rowsum,
                               int* __restrict__ row_cnt, int* __restrict__ count) {
    int i = blockIdx.x * blockDim.x + threadIdx.x;
    if (i >= TBL) return;
    int key = tbl_key[i];
    if (key < 0) return;
    int t = tbl_val[i];
    int u = key >> 13, v = key & (Nn - 1);
    int edge = (t >= Ee) ? (t - Ee) : t;
    int p = atomicAdd(count, 1);
    rows[p] = u; cols[p] = v; eidx[p] = edge;
    atomicAdd(&row_cnt[u], 1);
#pragma unroll
    for (int hd = 0; hd < Hh; hd++)
        atomicAdd(&rowsum[hd * Nn + u], e[hd * Ee + edge]);
}

// ---------------------------------------------------------------------------
// Kernel 4: single-block exclusive scan of row counts -> row_start[0..N]
__global__ void scan_kernel(const int* __restrict__ row_cnt, int* __restrict__ row_start) {
    __shared__ int sums[1024];
    int t = threadIdx.x;
    int base = t * 8;
    int local[8];
    int s = 0;
#pragma unroll
    for (int i = 0; i < 8; i++) { local[i] = s; s += row_cnt[base + i]; }
    sums[t] = s;
    __syncthreads();
    for (int off = 1; off < 1024; off <<= 1) {
        int v = 0;
        if (t >= off) v = sums[t - off];
        __syncthreads();
        if (t >= off) sums[t] += v;
        __syncthreads();
    }
    int prefix = (t == 0) ? 0 : sums[t - 1];
#pragma unroll
    for (int i = 0; i < 8; i++) row_start[base + i] = prefix + local[i];
    if (t == 1023) row_start[Nn] = sums[1023];
}

// ---------------------------------------------------------------------------
// Kernel 5: fill CSR (cols + normalized per-head values)
__global__ void fill_kernel(const int* __restrict__ count,
                            const int* __restrict__ rows, const int* __restrict__ cols,
                            const int* __restrict__ eidx, const int* __restrict__ row_start,
                            int* __restrict__ row_fill, const float* __restrict__ e,
                            const float* __restrict__ rowsum,
                            int* __restrict__ csr_col, float* __restrict__ csr_val) {
    int p = blockIdx.x * blockDim.x + threadIdx.x;
    if (p >= *count) return;
    int u = rows[p];
    int slot = row_start[u] + atomicAdd(&row_fill[u], 1);
    csr_col[slot] = cols[p];
    int edge = eidx[p];
#pragma unroll
    for (int hd = 0; hd < Hh; hd++)
        csr_val[hd * (2 * Ee) + slot] = e[hd * Ee + edge] / rowsum[hd * Nn + u];
}

// ---------------------------------------------------------------------------
// Kernel 6: x = h; res = x   (reshape is flat-order-preserving)
__global__ void xinit_kernel(const float* __restrict__ h,
                             float* __restrict__ x, float* __restrict__ res) {
    int i = blockIdx.x * blockDim.x + threadIdx.x;
    if (i >= XLEN) return;
    float v = h[i];
    x[i] = v; res[i] = v;
}

// ---------------------------------------------------------------------------
// Kernel 7: gather SpMV, one wave (64 lanes) per row; lane = (head, k).
//   y[hd][u][k]   = sum_v a_norm[hd][u][v] * x[hd][v][k]
//   res[hd][u][k] += y * inv_fact ; on last iter also store f32 out.
__global__ void spmv_kernel(const int* __restrict__ row_start, const int* __restrict__ csr_col,
                            const float* __restrict__ csr_val, const float* __restrict__ x,
                            float* __restrict__ y, float* __restrict__ res,
                            float inv_fact, float* __restrict__ out) {
    int wave = blockIdx.x * (blockDim.x >> 6) + (threadIdx.x >> 6);
    if (wave >= Nn) return;
    int lane = threadIdx.x & 63;
    int hd = lane >> 4, k = lane & 15;
    int u = wave;
    int s = row_start[u], send = row_start[u + 1];
    float acc = 0.0f;
    for (int p = s; p < send; p++) {
        int v = csr_col[p];                          // wave-uniform -> broadcast
        float coef = csr_val[hd * (2 * Ee) + p];     // 4 distinct addrs per wave
        acc += coef * x[(hd * Nn + v) * DK + k];     // 64B coalesced per head
    }
    int oi = (hd * Nn + u) * DK + k;
    y[oi] = acc;
    float r = res[oi] + acc * inv_fact;
    res[oi] = r;
    if (out) out[oi] = r;
}

// ---------------------------------------------------------------------------
extern "C" void kernel_launch(void* const* d_in, const int* in_sizes, int n_in,
                              void* d_out, int out_size, void* d_ws, size_t ws_size,
                              hipStream_t stream) {
    const float* h = (const float*)d_in[0];
    const float* e = (const float*)d_in[1];
    const int* src = (const int*)d_in[2];
    const int* dst = (const int*)d_in[3];
    float* out = (float*)d_out;

    // Workspace carve-up (~22.5 MB total)
    char* ws = (char*)d_ws;
    size_t off = 0;
    auto alloc = [&](size_t bytes) -> void* {
        void* p = ws + off;
        off = (off + bytes + 255) & ~(size_t)255;
        return p;
    };
    int*   tbl_key   = (int*)  alloc((size_t)TBL * 4);
    int*   tbl_val   = (int*)  alloc((size_t)TBL * 4);
    int*   rows      = (int*)  alloc((size_t)2 * Ee * 4);
    int*   cols      = (int*)  alloc((size_t)2 * Ee * 4);
    int*   eidx      = (int*)  alloc((size_t)2 * Ee * 4);
    float* rowsum    = (float*)alloc((size_t)Hh * Nn * 4);
    int*   row_cnt   = (int*)  alloc((size_t)Nn * 4);
    int*   row_fill  = (int*)  alloc((size_t)Nn * 4);
    int*   row_start = (int*)  alloc((size_t)(Nn + 1) * 4);
    int*   count     = (int*)  alloc(256);
    int*   csr_col   = (int*)  alloc((size_t)2 * Ee * 4);
    float* csr_val   = (float*)alloc((size_t)Hh * 2 * Ee * 4);
    float* xbuf      = (float*)alloc((size_t)XLEN * 4);
    float* ybuf      = (float*)alloc((size_t)XLEN * 4);
    float* res       = (float*)alloc((size_t)XLEN * 4);

    const int tpb = 256;

    init_kernel<<<TBL / tpb, tpb, 0, stream>>>(tbl_key, tbl_val, rowsum, row_cnt, row_fill, count);
    insert_kernel<<<(2 * Ee) / tpb, tpb, 0, stream>>>(src, dst, tbl_key, tbl_val);
    compact_kernel<<<TBL / tpb, tpb, 0, stream>>>(tbl_key, tbl_val, e, rows, cols, eidx,
                                                  rowsum, row_cnt, count);
    scan_kernel<<<1, 1024, 0, stream>>>(row_cnt, row_start);
    fill_kernel<<<(2 * Ee) / tpb, tpb, 0, stream>>>(count, rows, cols, eidx, row_start,
                                                    row_fill, e, rowsum, csr_col, csr_val);
    xinit_kernel<<<XLEN / tpb, tpb, 0, stream>>>(h, xbuf, res);

    const float invf[7] = {0.f, 1.f, 0.5f, 1.f / 6.f, 1.f / 24.f, 1.f / 120.f, 1.f / 720.f};
    float* xp = xbuf;
    float* yp = ybuf;
    for (int i = 1; i <= 6; i++) {
        spmv_kernel<<<Nn / 4, 256, 0, stream>>>(row_start, csr_col, csr_val, xp, yp, res,
                                                invf[i], (i == 6) ? out : nullptr);
        float* t = xp; xp = yp; yp = t;
    }
}

// Round 4
// 261.193 us; speedup vs baseline: 1.7755x; 1.7755x over previous
//
#include <hip/hip_runtime.h>
#include <hip/hip_bf16.h>

// Problem constants (fixed by reference)
static constexpr int Nn  = 8192;     // nodes
static constexpr int Hh  = 4;        // heads
static constexpr int Ee  = 131072;   // edges
static constexpr int DK  = 16;       // per-head feature dim
static constexpr int TBL = 1 << 20;  // hash table slots (load ~0.25)
static constexpr int TBLMASK = TBL - 1;
static constexpr unsigned KEYMASK = (1u << 26) - 1;   // key = (u<<13)|v, 26 bits
static constexpr int XLEN = Hh * Nn * DK;  // 524288 floats
// State layout is [hd][m][k] flat = hd*131072 + m*16 + k — EXACTLY the flat
// order of h.reshape(H,N,16) and of result.reshape(N,64). Verified passing in
// round 2. (NOT [m][hd*16+k]: the reshape chops flat h into 4 contiguous
// chunks; reshaped node m of head hd is real node hd*2048+m/4, quarter m%4.)

// ---------------------------------------------------------------------------
// Kernel 1: zero hash table + row counters
__global__ void zero_kernel(unsigned long long* __restrict__ tbl,
                            int* __restrict__ row_cnt, int* __restrict__ row_fill) {
    int i = blockIdx.x * blockDim.x + threadIdx.x;
    if (i < TBL) tbl[i] = 0ull;
    if (i < Nn) { row_cnt[i] = 0; row_fill[i] = 0; }
}

// ---------------------------------------------------------------------------
// Kernel 2: insert all 2E directed entries; slot holds packed ((t+1)<<26)|key.
// Winner per (u,v) = max combined t  (numpy last-write-wins scatter order:
//   t < E : (src,dst) first scatter; t >= E : (dst,src) second scatter).
// Single 64-bit CAS per insert in the common (no-duplicate) case.
__global__ void insert_kernel(const int* __restrict__ src, const int* __restrict__ dst,
                              unsigned long long* __restrict__ tbl) {
    int t = blockIdx.x * blockDim.x + threadIdx.x;
    if (t >= 2 * Ee) return;
    int u, v;
    if (t < Ee) { u = src[t]; v = dst[t]; }
    else        { u = dst[t - Ee]; v = src[t - Ee]; }
    unsigned key = ((unsigned)u << 13) | (unsigned)v;   // N = 2^13
    unsigned long long want = (((unsigned long long)(t + 1)) << 26) | key;
    unsigned idx = ((key * 2654435761u) >> 6) & TBLMASK;
    while (true) {
        unsigned long long cur = tbl[idx];              // racy peek; truth via CAS
        if (cur == 0ull) {
            unsigned long long old = atomicCAS(&tbl[idx], 0ull, want);
            if (old == 0ull) return;
            cur = old;
        }
        if ((unsigned)(cur & KEYMASK) == key) {
            while (cur < want) {                        // rank-max update
                unsigned long long old = atomicCAS(&tbl[idx], cur, want);
                if (old == cur) break;
                cur = old;
            }
            return;
        }
        idx = (idx + 1) & TBLMASK;                      // probe next slot
    }
}

// ---------------------------------------------------------------------------
// Kernel 3: per-row entry count (histogram over occupied slots)
__global__ void count_kernel(const unsigned long long* __restrict__ tbl,
                             int* __restrict__ row_cnt) {
    int i = blockIdx.x * blockDim.x + threadIdx.x;
    if (i >= TBL) return;
    unsigned long long cur = tbl[i];
    if (cur == 0ull) return;
    int u = (int)((cur & KEYMASK) >> 13);
    atomicAdd(&row_cnt[u], 1);
}

// ---------------------------------------------------------------------------
// Kernel 4: single-block exclusive scan of row counts -> row_start[0..N]
__global__ void scan_kernel(const int* __restrict__ row_cnt, int* __restrict__ row_start) {
    __shared__ int sums[1024];
    int t = threadIdx.x;
    int base = t * 8;
    int local[8];
    int s = 0;
#pragma unroll
    for (int i = 0; i < 8; i++) { local[i] = s; s += row_cnt[base + i]; }
    sums[t] = s;
    __syncthreads();
    for (int off = 1; off < 1024; off <<= 1) {
        int v = 0;
        if (t >= off) v = sums[t - off];
        __syncthreads();
        if (t >= off) sums[t] += v;
        __syncthreads();
    }
    int prefix = (t == 0) ? 0 : sums[t - 1];
#pragma unroll
    for (int i = 0; i < 8; i++) row_start[base + i] = prefix + local[i];
    if (t == 1023) row_start[Nn] = sums[1023];
}

// ---------------------------------------------------------------------------
// Kernel 5: fill CSR cols + edge ids (bump-allocate within row)
__global__ void fill_kernel(const unsigned long long* __restrict__ tbl,
                            const int* __restrict__ row_start, int* __restrict__ row_fill,
                            int* __restrict__ csr_col, int* __restrict__ csr_eidx) {
    int i = blockIdx.x * blockDim.x + threadIdx.x;
    if (i >= TBL) return;
    unsigned long long cur = tbl[i];
    if (cur == 0ull) return;
    unsigned key = (unsigned)(cur & KEYMASK);
    int u = (int)(key >> 13), v = (int)(key & (Nn - 1));
    int t = (int)(cur >> 26) - 1;
    int edge = (t >= Ee) ? (t - Ee) : t;
    int slot = row_start[u] + atomicAdd(&row_fill[u], 1);
    csr_col[slot] = v;
    csr_eidx[slot] = edge;
}

// ---------------------------------------------------------------------------
// Kernel 6: per-row rowsum (wave shfl-reduce, NO atomics) + normalized vals
//   val4[4*p + hd] = e[hd][edge(p)] / rowsum[hd][u]
__global__ void rowsumval_kernel(const int* __restrict__ row_start,
                                 const int* __restrict__ csr_eidx,
                                 const float* __restrict__ e,
                                 float* __restrict__ val4) {
    int wave = blockIdx.x * (blockDim.x >> 6) + (threadIdx.x >> 6);
    if (wave >= Nn) return;
    int lane = threadIdx.x & 63;
    int s = row_start[wave], send = row_start[wave + 1];
    float sum0 = 0.f, sum1 = 0.f, sum2 = 0.f, sum3 = 0.f;
    for (int p = s + lane; p < send; p += 64) {
        int edge = csr_eidx[p];
        sum0 += e[0 * Ee + edge];
        sum1 += e[1 * Ee + edge];
        sum2 += e[2 * Ee + edge];
        sum3 += e[3 * Ee + edge];
    }
#pragma unroll
    for (int off = 32; off > 0; off >>= 1) {
        sum0 += __shfl_xor(sum0, off, 64);
        sum1 += __shfl_xor(sum1, off, 64);
        sum2 += __shfl_xor(sum2, off, 64);
        sum3 += __shfl_xor(sum3, off, 64);
    }
    float inv0 = 1.f / sum0, inv1 = 1.f / sum1, inv2 = 1.f / sum2, inv3 = 1.f / sum3;
    for (int p = s + lane; p < send; p += 64) {
        int edge = csr_eidx[p];
        val4[4 * p + 0] = e[0 * Ee + edge] * inv0;
        val4[4 * p + 1] = e[1 * Ee + edge] * inv1;
        val4[4 * p + 2] = e[2 * Ee + edge] * inv2;
        val4[4 * p + 3] = e[3 * Ee + edge] * inv3;
    }
}

// ---------------------------------------------------------------------------
// Kernel 7: gather SpMV, one wave per row u; lane = (hd, k), hd=lane>>4,k=lane&15.
// State layout [hd][m][k]:  x[hd][m][k] at flat hd*Nn*DK + m*DK + k.
//   y[hd][u][k]      = sum_p val4[p][hd] * x[hd][col(p)][k]   (4 x 64B per entry)
//   res_out[hd][u][k]= res_in[hd][u][k] + y*inv_fact
// Sweep 1: xin = res_in = h.  Sweep 6: res_out = d_out.
__global__ void spmv_kernel(const int* __restrict__ row_start, const int* __restrict__ csr_col,
                            const float* __restrict__ val4, const float* __restrict__ xin,
                            float* __restrict__ y, const float* __restrict__ res_in,
                            float* __restrict__ res_out, float inv_fact) {
    int wave = blockIdx.x * (blockDim.x >> 6) + (threadIdx.x >> 6);
    if (wave >= Nn) return;
    int lane = threadIdx.x & 63;
    int hd = lane >> 4, k = lane & 15;
    int s = row_start[wave], send = row_start[wave + 1];
    const float* xh = xin + hd * (Nn * DK) + k;
    float acc = 0.0f;
    for (int p = s; p < send; p++) {
        int v = csr_col[p];                     // wave-uniform
        float coef = val4[4 * p + hd];          // 16B shared by wave
        acc += coef * xh[v * DK];               // 64B contiguous per head group
    }
    int oi = (hd * Nn + wave) * DK + k;
    y[oi] = acc;
    res_out[oi] = res_in[oi] + acc * inv_fact;
}

// ---------------------------------------------------------------------------
extern "C" void kernel_launch(void* const* d_in, const int* in_sizes, int n_in,
                              void* d_out, int out_size, void* d_ws, size_t ws_size,
                              hipStream_t stream) {
    const float* h = (const float*)d_in[0];
    const float* e = (const float*)d_in[1];
    const int* src = (const int*)d_in[2];
    const int* dst = (const int*)d_in[3];
    float* out = (float*)d_out;

    // Workspace carve-up (~18 MB)
    char* ws = (char*)d_ws;
    size_t off = 0;
    auto alloc = [&](size_t bytes) -> void* {
        void* p = ws + off;
        off = (off + bytes + 255) & ~(size_t)255;
        return p;
    };
    unsigned long long* tbl = (unsigned long long*)alloc((size_t)TBL * 8);
    int*   row_cnt   = (int*)  alloc((size_t)Nn * 4);
    int*   row_fill  = (int*)  alloc((size_t)Nn * 4);
    int*   row_start = (int*)  alloc((size_t)(Nn + 1) * 4);
    int*   csr_col   = (int*)  alloc((size_t)2 * Ee * 4);
    int*   csr_eidx  = (int*)  alloc((size_t)2 * Ee * 4);
    float* val4      = (float*)alloc((size_t)4 * 2 * Ee * 4);
    float* ybufA     = (float*)alloc((size_t)XLEN * 4);
    float* ybufB     = (float*)alloc((size_t)XLEN * 4);
    float* res       = (float*)alloc((size_t)XLEN * 4);

    const int tpb = 256;

    zero_kernel<<<TBL / tpb, tpb, 0, stream>>>(tbl, row_cnt, row_fill);
    insert_kernel<<<(2 * Ee) / tpb, tpb, 0, stream>>>(src, dst, tbl);
    count_kernel<<<TBL / tpb, tpb, 0, stream>>>(tbl, row_cnt);
    scan_kernel<<<1, 1024, 0, stream>>>(row_cnt, row_start);
    fill_kernel<<<TBL / tpb, tpb, 0, stream>>>(tbl, row_start, row_fill, csr_col, csr_eidx);
    rowsumval_kernel<<<Nn / 4, tpb, 0, stream>>>(row_start, csr_eidx, e, val4);

    const float invf[7] = {0.f, 1.f, 0.5f, 1.f / 6.f, 1.f / 24.f, 1.f / 120.f, 1.f / 720.f};
    // sweep 1: x = h, res_in = h, res_out = res, y -> ybufA
    spmv_kernel<<<Nn / 4, tpb, 0, stream>>>(row_start, csr_col, val4, h, ybufA, h, res, invf[1]);
    // sweeps 2..5: ping-pong y buffers, res in-place
    float* xp = ybufA;
    float* yp = ybufB;
    for (int i = 2; i <= 5; i++) {
        spmv_kernel<<<Nn / 4, tpb, 0, stream>>>(row_start, csr_col, val4, xp, yp, res, res, invf[i]);
        float* t = xp; xp = yp; yp = t;
    }
    // sweep 6: res_out = d_out
    spmv_kernel<<<Nn / 4, tpb, 0, stream>>>(row_start, csr_col, val4, xp, yp, res, out, invf[6]);
}